// Round 3
// baseline (70.438 us; speedup 1.0000x reference)
//
#include <hip/hip_runtime.h>
#include <cstdint>

#define B_ 16
#define N_ 4096
#define C_ 1024
#define K_ 64

// ws float-index layout
#define WS_WBAR   0                    // 1024 f32
#define WS_BBAR   1024                 // 1 f32
#define WS_SCORES 2048                 // B*N f32
#define WS_PART   (WS_SCORES + B_*N_)  // 64*1024 f32 partials for wbar

// ---- stage 1: partial column sums of W (blocks 0..63); block 64: bbar ----
__global__ __launch_bounds__(256) void wsum1_kernel(const float* __restrict__ W,
                                                    const float* __restrict__ b,
                                                    float* __restrict__ ws) {
    int j = blockIdx.x, t = threadIdx.x;
    if (j == 64) {                                   // bbar = mean(b)
        float4 bv = ((const float4*)b)[t];
        float sb = bv.x + bv.y + bv.z + bv.w;
        for (int off = 32; off; off >>= 1) sb += __shfl_xor(sb, off);
        __shared__ float red[4];
        if ((t & 63) == 0) red[t >> 6] = sb;
        __syncthreads();
        if (t == 0) ws[WS_BBAR] = (red[0] + red[1] + red[2] + red[3]) * (1.0f / C_);
        return;
    }
    const float4* W4 = (const float4*)W;
    float4 s = {0.f, 0.f, 0.f, 0.f};
#pragma unroll
    for (int d = 0; d < 16; ++d) {
        float4 w = W4[(j * 16 + d) * 256 + t];       // coalesced 4KB/row
        s.x += w.x; s.y += w.y; s.z += w.z; s.w += w.w;
    }
    ((float4*)(ws + WS_PART))[j * 256 + t] = s;
}

// ---- stage 2: reduce 64 partials -> wbar ; 4 blocks x 256 cols ----
__global__ __launch_bounds__(256) void wsum2_kernel(float* __restrict__ ws) {
    int col = blockIdx.x * 256 + threadIdx.x;
    float s = 0.f;
#pragma unroll 8
    for (int j = 0; j < 64; ++j) s += ws[WS_PART + j * 1024 + col];  // 1KB coalesced
    ws[WS_WBAR + col] = s * (1.0f / C_);
}

// ---- scores: one wave per 4 rows, 8 waves/block -> 32 rows/block ----
__global__ __launch_bounds__(512) void scores_kernel(const float* __restrict__ x,
                                                     float* ws) {
    __shared__ float lw[C_];
    int t = threadIdx.x;
    float bbar = ws[WS_BBAR];
    if (t < 256) ((float4*)lw)[t] = ((const float4*)(ws + WS_WBAR))[t];
    __syncthreads();
    int wave = t >> 6, lane = t & 63;
    int row0 = blockIdx.x * 32 + wave * 4;
    const float4* x4 = (const float4*)x;
    const float4* lw4 = (const float4*)lw;
    float a0 = 0.f, a1 = 0.f, a2 = 0.f, a3 = 0.f;
#pragma unroll
    for (int q = 0; q < 4; ++q) {
        float4 wv = lw4[q * 64 + lane];
        float4 v0 = x4[(row0 + 0) * 256 + q * 64 + lane];
        float4 v1 = x4[(row0 + 1) * 256 + q * 64 + lane];
        float4 v2 = x4[(row0 + 2) * 256 + q * 64 + lane];
        float4 v3 = x4[(row0 + 3) * 256 + q * 64 + lane];
        a0 += v0.x * wv.x + v0.y * wv.y + v0.z * wv.z + v0.w * wv.w;
        a1 += v1.x * wv.x + v1.y * wv.y + v1.z * wv.z + v1.w * wv.w;
        a2 += v2.x * wv.x + v2.y * wv.y + v2.z * wv.z + v2.w * wv.w;
        a3 += v3.x * wv.x + v3.y * wv.y + v3.z * wv.z + v3.w * wv.w;
    }
    for (int off = 32; off; off >>= 1) {
        a0 += __shfl_xor(a0, off);
        a1 += __shfl_xor(a1, off);
        a2 += __shfl_xor(a2, off);
        a3 += __shfl_xor(a3, off);
    }
    if (lane == 0) {
        ws[WS_SCORES + row0 + 0] = a0 + bbar;
        ws[WS_SCORES + row0 + 1] = a1 + bbar;
        ws[WS_SCORES + row0 + 2] = a2 + bbar;
        ws[WS_SCORES + row0 + 3] = a3 + bbar;
    }
}

// sortable-uint mapping for f32 (monotonic)
__device__ __forceinline__ unsigned su_(float f) {
    unsigned u = __float_as_uint(f);
    return (u & 0x80000000u) ? ~u : (u | 0x80000000u);
}
__device__ __forceinline__ float isu_(unsigned u) {
    unsigned v = (u & 0x80000000u) ? (u ^ 0x80000000u) : ~u;
    return __uint_as_float(v);
}

// ---- per-batch: softmax stats + radix-select top-64 + mask + gather out ----
__global__ __launch_bounds__(256) void topk_out_kernel(const float* __restrict__ x,
                                                       float* ws,
                                                       float* __restrict__ out,
                                                       float* __restrict__ mask_out) {
    __shared__ unsigned hist[4096];                 // 16 KB
    __shared__ unsigned long long cand[4096];       // 32 KB (worst-case capacity)
    __shared__ float redf[4];
    __shared__ unsigned scnt;
    __shared__ int sbin;
    __shared__ int   li[K_];
    __shared__ float la[K_];
    int b = blockIdx.x, t = threadIdx.x;
    int wid = t >> 6, lane = t & 63;
    const float* srow = ws + WS_SCORES + b * N_;

    float v[16];
#pragma unroll
    for (int e = 0; e < 16; ++e) v[e] = srow[e * 256 + t];   // thread owns idx e*256+t

#pragma unroll
    for (int e = 0; e < 16; ++e) hist[e * 256 + t] = 0;
    if (t == 0) scnt = 0;

    // global max
    float m = v[0];
#pragma unroll
    for (int e = 1; e < 16; ++e) m = fmaxf(m, v[e]);
    for (int off = 32; off; off >>= 1) m = fmaxf(m, __shfl_xor(m, off));
    if (lane == 0) redf[wid] = m;
    __syncthreads();                                // hist zeroed + redf(max) ready
    m = fmaxf(fmaxf(redf[0], redf[1]), fmaxf(redf[2], redf[3]));

    // softmax denominator over ALL N (reference: softmax then mask)
    float dsum = 0.f;
#pragma unroll
    for (int e = 0; e < 16; ++e) dsum += expf(v[e] - m);
    for (int off = 32; off; off >>= 1) dsum += __shfl_xor(dsum, off);

    // histogram of top-12 bits of sortable key
#pragma unroll
    for (int e = 0; e < 16; ++e) atomicAdd(&hist[su_(v[e]) >> 20], 1u);

    __syncthreads();                                // everyone done reading redf(max)
    if (lane == 0) redf[wid] = dsum;
    __syncthreads();                                // redf(denom) + hist ready
    float denom = redf[0] + redf[1] + redf[2] + redf[3];

    // wave 0: suffix scan over 4096 bins to find the rank-64 threshold bin
    if (wid == 0) {
        int base = lane * 64;
        unsigned s = 0;
        for (int j = 0; j < 64; ++j) s += hist[base + j];
        unsigned suf = s;                           // inclusive suffix over lane chunks
        for (int off = 1; off < 64; off <<= 1) {
            unsigned o = __shfl_down(suf, off);
            if (lane + off < 64) suf += o;
        }
        unsigned above = suf - s;                   // count in higher chunks
        if (above < (unsigned)K_ && above + s >= (unsigned)K_) {
            unsigned run = above;
            for (int j = 63; j >= 0; --j) {
                unsigned c = hist[base + j];
                if (run < (unsigned)K_ && run + c >= (unsigned)K_) sbin = base + j;
                run += c;
            }
        }
    }
    __syncthreads();                                // sbin ready
    int Bn = sbin;

    // collect candidates (bucket >= threshold bin); keys unique (idx in low bits)
#pragma unroll
    for (int e = 0; e < 16; ++e) {
        unsigned k32 = su_(v[e]);
        if ((int)(k32 >> 20) >= Bn) {
            unsigned p = atomicAdd(&scnt, 1u);
            cand[p] = ((unsigned long long)k32 << 32) |
                      (unsigned long long)(0xFFFFFFFFu - (unsigned)(e * 256 + t));
        }
    }
    // zero the mask row (coalesced) before winners overwrite
#pragma unroll
    for (int e = 0; e < 16; ++e) mask_out[b * N_ + e * 256 + t] = 0.0f;
    __syncthreads();                                // cand/scnt ready

    unsigned mc = scnt;
    for (unsigned i = t; i < mc; i += 256) {
        unsigned long long ki = cand[i];
        unsigned r = 0;
        for (unsigned j = 0; j < mc; ++j) r += (cand[j] > ki) ? 1u : 0u;
        if (r < (unsigned)K_) {                     // exact rank; tie -> lower idx wins
            unsigned widx = 0xFFFFFFFFu - (unsigned)(ki & 0xFFFFFFFFu);
            float sc = isu_((unsigned)(ki >> 32));
            li[r] = (int)widx;
            la[r] = expf(sc - m) / denom;
            mask_out[b * N_ + widx] = 1.0f;
        }
    }
    __syncthreads();                                // li/la ready

    // gather: out[b,:] = sum_r la[r] * x[b, li[r], :]
    const float4* x4 = (const float4*)x;
    float4 acc = {0.f, 0.f, 0.f, 0.f};
#pragma unroll 8
    for (int r = 0; r < K_; ++r) {
        float a = la[r];
        float4 xv = x4[(size_t)(b * N_ + li[r]) * 256 + t];  // coalesced 4KB/row
        acc.x += a * xv.x; acc.y += a * xv.y; acc.z += a * xv.z; acc.w += a * xv.w;
    }
    ((float4*)out)[b * 256 + t] = acc;
}

extern "C" void kernel_launch(void* const* d_in, const int* in_sizes, int n_in,
                              void* d_out, int out_size, void* d_ws, size_t ws_size,
                              hipStream_t stream) {
    const float* x = (const float*)d_in[0];   // (B,N,C) f32
    const float* W = (const float*)d_in[1];   // (C,C) f32
    const float* b = (const float*)d_in[2];   // (C,) f32
    float* out  = (float*)d_out;              // (B,C) then (B,N) mask
    float* mask = out + B_ * C_;
    float* ws   = (float*)d_ws;

    wsum1_kernel   <<<65,          256, 0, stream>>>(W, b, ws);
    wsum2_kernel   <<<4,           256, 0, stream>>>(ws);
    scores_kernel  <<<B_ * N_ / 32, 512, 0, stream>>>(x, ws);
    topk_out_kernel<<<B_,          256, 0, stream>>>(x, ws, out, mask);
}

// Round 4
// 65.239 us; speedup vs baseline: 1.0797x; 1.0797x over previous
//
#include <hip/hip_runtime.h>
#include <cstdint>

#define B_ 16
#define N_ 4096
#define C_ 1024
#define K_ 64

typedef float vf4 __attribute__((ext_vector_type(4)));

// ws float-index layout
#define WS_WBAR   0                    // 1024 f32
#define WS_BBAR   1024                 // 1 f32
#define WS_SCORES 2048                 // B*N f32
#define WS_TIDX   (WS_SCORES + B_*N_)  // B*K int
#define WS_TATT   (WS_TIDX + B_*K_)    // B*K f32
#define WS_PART   (WS_TATT + B_*K_)    // 64*1024 f32 partials for wbar

// ---- stage 1: partial column sums of W (blocks 0..63); block 64: bbar ----
__global__ __launch_bounds__(256) void wsum1_kernel(const float* __restrict__ W,
                                                    const float* __restrict__ b,
                                                    float* __restrict__ ws) {
    int j = blockIdx.x, t = threadIdx.x;
    if (j == 64) {                                   // bbar = mean(b)
        float4 bv = ((const float4*)b)[t];
        float sb = bv.x + bv.y + bv.z + bv.w;
        for (int off = 32; off; off >>= 1) sb += __shfl_xor(sb, off);
        __shared__ float red[4];
        if ((t & 63) == 0) red[t >> 6] = sb;
        __syncthreads();
        if (t == 0) ws[WS_BBAR] = (red[0] + red[1] + red[2] + red[3]) * (1.0f / C_);
        return;
    }
    const float4* W4 = (const float4*)W;
    float4 s = {0.f, 0.f, 0.f, 0.f};
#pragma unroll
    for (int d = 0; d < 16; ++d) {
        float4 w = W4[(j * 16 + d) * 256 + t];       // coalesced 4KB/row
        s.x += w.x; s.y += w.y; s.z += w.z; s.w += w.w;
    }
    ((float4*)(ws + WS_PART))[j * 256 + t] = s;
}

// ---- stage 2: reduce 64 partials -> wbar ; 4 blocks x 256 cols ----
__global__ __launch_bounds__(256) void wsum2_kernel(float* __restrict__ ws) {
    int col = blockIdx.x * 256 + threadIdx.x;
    float s = 0.f;
#pragma unroll 8
    for (int j = 0; j < 64; ++j) s += ws[WS_PART + j * 1024 + col];  // 1KB coalesced
    ws[WS_WBAR + col] = s * (1.0f / C_);
}

// ---- scores: one wave per row, 8 waves/block ; nontemporal x reads ----
__global__ __launch_bounds__(512) void scores_kernel(const float* __restrict__ x,
                                                     float* ws) {
    __shared__ float lw[C_];
    int t = threadIdx.x;
    float bbar = ws[WS_BBAR];
    if (t < 256) ((float4*)lw)[t] = ((const float4*)(ws + WS_WBAR))[t];
    __syncthreads();
    int wave = t >> 6, lane = t & 63;
    int row = blockIdx.x * 8 + wave;                 // row in [0, B*N)
    const vf4* x4 = (const vf4*)x;
    const float4* lw4 = (const float4*)lw;
    float acc = 0.f;
#pragma unroll
    for (int q = 0; q < 4; ++q) {
        vf4 xv = __builtin_nontemporal_load(x4 + (size_t)row * 256 + q * 64 + lane);
        float4 wv = lw4[q * 64 + lane];
        acc += xv.x * wv.x + xv.y * wv.y + xv.z * wv.z + xv.w * wv.w;
    }
    for (int off = 32; off; off >>= 1) acc += __shfl_xor(acc, off);
    if (lane == 0) ws[WS_SCORES + row] = acc + bbar;
}

// sortable-uint mapping for f32 (monotonic)
__device__ __forceinline__ unsigned su_(float f) {
    unsigned u = __float_as_uint(f);
    return (u & 0x80000000u) ? ~u : (u | 0x80000000u);
}
__device__ __forceinline__ float isu_(unsigned u) {
    unsigned v = (u & 0x80000000u) ? (u ^ 0x80000000u) : ~u;
    return __uint_as_float(v);
}

// ---- per-batch: softmax stats + radix-select top-64 + mask ----
__global__ __launch_bounds__(256) void topk_kernel(float* ws,
                                                   float* __restrict__ mask_out) {
    __shared__ unsigned hist[4096];                 // 16 KB
    __shared__ unsigned long long cand[4096];       // 32 KB (worst-case capacity)
    __shared__ float redf[4];
    __shared__ unsigned scnt;
    __shared__ int sbin;
    int b = blockIdx.x, t = threadIdx.x;
    int wid = t >> 6, lane = t & 63;
    const float* srow = ws + WS_SCORES + b * N_;

    float v[16];
#pragma unroll
    for (int e = 0; e < 16; ++e) v[e] = srow[e * 256 + t];   // thread owns idx e*256+t

#pragma unroll
    for (int e = 0; e < 16; ++e) hist[e * 256 + t] = 0;
    if (t == 0) scnt = 0;

    // global max
    float m = v[0];
#pragma unroll
    for (int e = 1; e < 16; ++e) m = fmaxf(m, v[e]);
    for (int off = 32; off; off >>= 1) m = fmaxf(m, __shfl_xor(m, off));
    if (lane == 0) redf[wid] = m;
    __syncthreads();                                // hist zeroed + redf(max) ready
    m = fmaxf(fmaxf(redf[0], redf[1]), fmaxf(redf[2], redf[3]));

    // softmax denominator over ALL N (reference: softmax then mask)
    float dsum = 0.f;
#pragma unroll
    for (int e = 0; e < 16; ++e) dsum += expf(v[e] - m);
    for (int off = 32; off; off >>= 1) dsum += __shfl_xor(dsum, off);

    // histogram of top-12 bits of sortable key
#pragma unroll
    for (int e = 0; e < 16; ++e) atomicAdd(&hist[su_(v[e]) >> 20], 1u);

    __syncthreads();                                // everyone done reading redf(max)
    if (lane == 0) redf[wid] = dsum;
    __syncthreads();                                // redf(denom) + hist ready
    float denom = redf[0] + redf[1] + redf[2] + redf[3];

    // wave 0: suffix scan over 4096 bins to find the rank-64 threshold bin
    if (wid == 0) {
        int base = lane * 64;
        unsigned s = 0;
        for (int j = 0; j < 64; ++j) s += hist[base + j];
        unsigned suf = s;                           // inclusive suffix over lane chunks
        for (int off = 1; off < 64; off <<= 1) {
            unsigned o = __shfl_down(suf, off);
            if (lane + off < 64) suf += o;
        }
        unsigned above = suf - s;                   // count in higher chunks
        if (above < (unsigned)K_ && above + s >= (unsigned)K_) {
            unsigned run = above;
            for (int j = 63; j >= 0; --j) {
                unsigned c = hist[base + j];
                if (run < (unsigned)K_ && run + c >= (unsigned)K_) sbin = base + j;
                run += c;
            }
        }
    }
    __syncthreads();                                // sbin ready
    int Bn = sbin;

    // collect candidates (bucket >= threshold bin); keys unique (idx in low bits)
#pragma unroll
    for (int e = 0; e < 16; ++e) {
        unsigned k32 = su_(v[e]);
        if ((int)(k32 >> 20) >= Bn) {
            unsigned p = atomicAdd(&scnt, 1u);
            cand[p] = ((unsigned long long)k32 << 32) |
                      (unsigned long long)(0xFFFFFFFFu - (unsigned)(e * 256 + t));
        }
    }
    // zero the mask row (coalesced) before winners overwrite
#pragma unroll
    for (int e = 0; e < 16; ++e) mask_out[b * N_ + e * 256 + t] = 0.0f;
    __syncthreads();                                // cand/scnt ready

    unsigned mc = scnt;
    int*   tidx = (int*)ws + WS_TIDX;
    float* tatt = ws + WS_TATT;
    for (unsigned i = t; i < mc; i += 256) {
        unsigned long long ki = cand[i];
        unsigned r = 0;
        for (unsigned j = 0; j < mc; ++j) r += (cand[j] > ki) ? 1u : 0u;
        if (r < (unsigned)K_) {                     // exact rank; tie -> lower idx wins
            unsigned widx = 0xFFFFFFFFu - (unsigned)(ki & 0xFFFFFFFFu);
            float sc = isu_((unsigned)(ki >> 32));
            tidx[b * K_ + r] = (int)widx;
            tatt[b * K_ + r] = expf(sc - m) / denom;
            mask_out[b * N_ + widx] = 1.0f;
        }
    }
}

// ---- out[b,c] = sum_r attn_r * x[b, idx_r, c] ; 4 column-chunks per batch ----
__global__ __launch_bounds__(256) void out_kernel(const float* __restrict__ x,
                                                  const float* __restrict__ ws,
                                                  float* __restrict__ out) {
    int blk = blockIdx.x;
    int b = blk >> 2, cc = blk & 3;
    int t = threadIdx.x;
    __shared__ int   li[K_];
    __shared__ float la[K_];
    if (t < K_) {
        li[t] = ((const int*)ws + WS_TIDX)[b * K_ + t];
        la[t] = (ws + WS_TATT)[b * K_ + t];
    }
    __syncthreads();
    int col = cc * 256 + t;
    float acc = 0.f;
#pragma unroll 8
    for (int r = 0; r < K_; ++r) {
        acc += la[r] * x[(size_t)(b * N_ + li[r]) * C_ + col];  // 1KB coalesced/row
    }
    out[b * C_ + col] = acc;
}

extern "C" void kernel_launch(void* const* d_in, const int* in_sizes, int n_in,
                              void* d_out, int out_size, void* d_ws, size_t ws_size,
                              hipStream_t stream) {
    const float* x = (const float*)d_in[0];   // (B,N,C) f32
    const float* W = (const float*)d_in[1];   // (C,C) f32
    const float* b = (const float*)d_in[2];   // (C,) f32
    float* out  = (float*)d_out;              // (B,C) then (B,N) mask
    float* mask = out + B_ * C_;
    float* ws   = (float*)d_ws;

    wsum1_kernel <<<65,           256, 0, stream>>>(W, b, ws);
    wsum2_kernel <<<4,            256, 0, stream>>>(ws);
    scores_kernel<<<B_ * N_ / 8,  512, 0, stream>>>(x, ws);
    topk_kernel  <<<B_,           256, 0, stream>>>(ws, mask);
    out_kernel   <<<B_ * 4,       256, 0, stream>>>(x, ws, out);
}